// Round 6
// baseline (154.638 us; speedup 1.0000x reference)
//
#include <hip/hip_runtime.h>

// Problem constants (from reference)
constexpr int L  = 250;   // layers
constexpr int T  = 600;   // traces
constexpr int A  = 30;    // angles
constexpr int AP = 32;    // padded angle dim (float4-aligned)
constexpr int KP = 256;   // padded k dim in workspace
constexpr int TRACE_STRIDE = KP * AP;   // 8192 floats per trace in ws
constexpr int WT_LD = 256;              // wmT leading dim (l padded 250->256)

// ---------------- Kernel W: wmT[k][l] = wm[l][k] ----------------
// wm rows are 1000 B apart; B's per-lane row-gather hit 8 cache lines per
// load instr (~60 us of L1 line fetches — the real R2-R5 bottleneck).
// Transposed, lanes read 8 contiguous floats = 1 line per instr.
__global__ __launch_bounds__(256)
void transpose_wm(const float* __restrict__ wm, float* __restrict__ wmT)
{
    const int l = blockIdx.x;     // 0..255 (blocks >=250 write pad zeros)
    const int k = threadIdx.x;    // 0..255
    if (k < L) {
        const float v = (l < L) ? wm[l * L + k] : 0.0f;   // coalesced read
        wmT[k * WT_LD + l] = v;                            // scattered write (62K lines total - cheap)
    }
}

// ---------------- Kernel A: ref[t][k][a] = Zoeppritz Rpp ----------------
// (unchanged from R5 — passed with absmax 1.95e-3)
__global__ __launch_bounds__(256)
void zoep_ref_kernel(const float* __restrict__ vp,
                     const float* __restrict__ vs,
                     const float* __restrict__ rho,
                     const float* __restrict__ theta,
                     float* __restrict__ ref_g)
{
    __shared__ float sth_s[32];
    __shared__ float cth_s[32];

    const int tid = threadIdx.x;
    if (tid < 32) {
        const float th = (tid < A) ? theta[tid] : 0.0f;
        sth_s[tid] = sinf(th);
        cth_s[tid] = cosf(th);
    }
    __syncthreads();

    const int b  = blockIdx.x;            // 0..4799
    const int t  = b >> 3;
    const int k  = ((b & 7) << 5) + (tid >> 3);   // 0..255
    const int aq = tid & 7;
    const int a0 = aq << 2;

    float res[4] = {0.f, 0.f, 0.f, 0.f};

    if (k < L - 1) {
        const float a1 = vp[k * T + t];
        const float a2 = vp[(k + 1) * T + t];
        const float b1 = vs[k * T + t];
        const float b2 = vs[(k + 1) * T + t];
        const float r1 = rho[k * T + t];
        const float r2 = rho[(k + 1) * T + t];

        const float ra1  = __builtin_amdgcn_rcpf(a1);
        const float rb1  = r1 * b1, rb2 = r2 * b2;
        const float ra1r = r1 * a1, ra2r = r2 * a2;

#pragma unroll
        for (int j = 0; j < 4; ++j) {
            const float sth = sth_s[a0 + j];
            const float cth = cth_s[a0 + j];

            const float p   = sth * ra1;
            const float s2  = p * a2;
            const float c2  = sqrtf(1.0f - s2 * s2);
            const float sp1 = p * b1;
            const float cp1 = sqrtf(1.0f - sp1 * sp1);
            const float sp2 = p * b2;
            const float cp2 = sqrtf(1.0f - sp2 * sp2);

            const float k1 = 1.0f - 2.0f * sp1 * sp1;
            const float k2 = 1.0f - 2.0f * sp2 * sp2;
            const float q1 = rb1 * k1;
            const float q2 = rb2 * k2;
            const float P1 = ra1r * k1;
            const float P2 = ra2r * k2;
            const float u1 = 2.0f * rb1 * sp1;
            const float u2 = 2.0f * rb2 * sp2;
            const float S1 = u1 * cp1;
            const float S2 = u2 * cp2;
            const float g1 = u1 * cth;
            const float g2 = u2 * c2;

            const float m00 = -sth, m01 = -cp1, m02 = s2,  m03 = cp2;
            const float m10 =  cth, m11 = -sp1, m12 = c2,  m13 = -sp2;
            const float m20 =  g1,  m21 =  q1,  m22 = g2,  m23 = q2;
            const float m30 = -P1,  m31 =  S1,  m32 = P2,  m33 = -S2;

            const float s3v = m01 * m12 - m11 * m02;
            const float s4v = m01 * m13 - m11 * m03;
            const float s5v = m02 * m13 - m12 * m03;
            const float c3v = m21 * m32 - m31 * m22;
            const float c4v = m21 * m33 - m31 * m23;
            const float c5v = m22 * m33 - m32 * m23;
            const float s0v = m00 * m11 - m10 * m01;
            const float s1v = m00 * m12 - m10 * m02;
            const float s2v = m00 * m13 - m10 * m03;
            const float c0v = m20 * m31 - m30 * m21;
            const float c1v = m20 * m32 - m30 * m22;
            const float c2v = m20 * m33 - m30 * m23;

            const float detM = s0v*c5v - s1v*c4v + s2v*c3v
                             + s3v*c2v - s4v*c1v + s5v*c0v;
            const float A0 = m11*c5v - m12*c4v + m13*c3v;   // minor(0,0)
            const float A3 = m21*s5v - m22*s4v + m23*s3v;   // minor(3,0)

            const float num = m00 * A0 - m30 * A3;
            res[j] = 1.0f - 2.0f * num * __builtin_amdgcn_rcpf(detM);
        }
        if (aq == 7) { res[2] = 0.0f; res[3] = 0.0f; }   // a = 30,31 pad
    }

    float4 o; o.x = res[0]; o.y = res[1]; o.z = res[2]; o.w = res[3];
    *(float4*)(ref_g + (size_t)t * TRACE_STRIDE + k * AP + a0) = o;
}

// ---------------- Kernel B: out[t][l][a] = sum_k wm[l][k] * ref[t][k][a] ----
// R2's proven shape (4 layers x 4 angles/thread, grid 1200, 64-k LDS slabs)
// with wm loads from wmT: per-k scalar loads, lanes (lg 0..7) read 8
// CONTIGUOUS floats = 1 cache line per instr (was 8 lines via row gather).
__global__ __launch_bounds__(256)
void zoep_gemm_kernel(const float* __restrict__ wmT,
                      const float* __restrict__ ref_g,
                      float* __restrict__ out)
{
    __shared__ float4 rs4[512];            // 8 KB k-slab of ref

    const int tid = threadIdx.x;
    const int b   = blockIdx.x;            // 0..1199
    const int t   = b >> 1;
    const int l0  = (b & 1) * 128;

    const int aq = tid & 7;                // angle quad: a = 4*aq..4*aq+3
    const int lg = tid >> 3;               // 0..31; layers l0+lg+32*i

    int lcol[4]; bool lvalid[4];
#pragma unroll
    for (int i = 0; i < 4; ++i) {
        const int l = l0 + lg + 32 * i;
        lvalid[i] = (l < L);
        lcol[i]   = lvalid[i] ? l : (L - 1);   // clamped wmT column
    }

    const float4* __restrict__ rg4 =
        (const float4*)(ref_g + (size_t)t * TRACE_STRIDE);   // rg4[k*8 + aq]

    float acc[4][4];
#pragma unroll
    for (int i = 0; i < 4; ++i)
#pragma unroll
        for (int j = 0; j < 4; ++j) acc[i][j] = 0.0f;

    for (int s = 0; s < 4; ++s) {
        const int k0 = s * 64;
        __syncthreads();
        rs4[tid]       = rg4[(k0 << 3) + tid];        // 64x32 slab, coalesced
        rs4[tid + 256] = rg4[(k0 << 3) + tid + 256];
        __syncthreads();

        const int kmax = (L - k0 < 64) ? (L - k0) : 64;   // 64,64,64,58
        const float* wk = wmT + k0 * WT_LD;               // row k0 of wmT

#pragma unroll 4
        for (int kk = 0; kk < kmax; kk += 2) {
            const float* w0p = wk + kk * WT_LD;       // wmT row k0+kk
            const float* w1p = w0p + WT_LD;           // wmT row k0+kk+1
            const float wA0 = w0p[lcol[0]];           // 8 contiguous lanes
            const float wB0 = w0p[lcol[1]];           // -> 1 line per instr
            const float wC0 = w0p[lcol[2]];
            const float wD0 = w0p[lcol[3]];
            const float wA1 = w1p[lcol[0]];
            const float wB1 = w1p[lcol[1]];
            const float wC1 = w1p[lcol[2]];
            const float wD1 = w1p[lcol[3]];
            const float4 r0 = rs4[kk * 8 + aq];       // 8-way bcast, no conflict
            const float4 r1 = rs4[kk * 8 + 8 + aq];

            acc[0][0] = fmaf(wA0, r0.x, acc[0][0]);
            acc[0][1] = fmaf(wA0, r0.y, acc[0][1]);
            acc[0][2] = fmaf(wA0, r0.z, acc[0][2]);
            acc[0][3] = fmaf(wA0, r0.w, acc[0][3]);
            acc[1][0] = fmaf(wB0, r0.x, acc[1][0]);
            acc[1][1] = fmaf(wB0, r0.y, acc[1][1]);
            acc[1][2] = fmaf(wB0, r0.z, acc[1][2]);
            acc[1][3] = fmaf(wB0, r0.w, acc[1][3]);
            acc[2][0] = fmaf(wC0, r0.x, acc[2][0]);
            acc[2][1] = fmaf(wC0, r0.y, acc[2][1]);
            acc[2][2] = fmaf(wC0, r0.z, acc[2][2]);
            acc[2][3] = fmaf(wC0, r0.w, acc[2][3]);
            acc[3][0] = fmaf(wD0, r0.x, acc[3][0]);
            acc[3][1] = fmaf(wD0, r0.y, acc[3][1]);
            acc[3][2] = fmaf(wD0, r0.z, acc[3][2]);
            acc[3][3] = fmaf(wD0, r0.w, acc[3][3]);

            acc[0][0] = fmaf(wA1, r1.x, acc[0][0]);
            acc[0][1] = fmaf(wA1, r1.y, acc[0][1]);
            acc[0][2] = fmaf(wA1, r1.z, acc[0][2]);
            acc[0][3] = fmaf(wA1, r1.w, acc[0][3]);
            acc[1][0] = fmaf(wB1, r1.x, acc[1][0]);
            acc[1][1] = fmaf(wB1, r1.y, acc[1][1]);
            acc[1][2] = fmaf(wB1, r1.z, acc[1][2]);
            acc[1][3] = fmaf(wB1, r1.w, acc[1][3]);
            acc[2][0] = fmaf(wC1, r1.x, acc[2][0]);
            acc[2][1] = fmaf(wC1, r1.y, acc[2][1]);
            acc[2][2] = fmaf(wC1, r1.z, acc[2][2]);
            acc[2][3] = fmaf(wC1, r1.w, acc[2][3]);
            acc[3][0] = fmaf(wD1, r1.x, acc[3][0]);
            acc[3][1] = fmaf(wD1, r1.y, acc[3][1]);
            acc[3][2] = fmaf(wD1, r1.z, acc[3][2]);
            acc[3][3] = fmaf(wD1, r1.w, acc[3][3]);
        }
    }

    // store out[t][l][a] (fp32); aq==7 has only angles 28,29
    float* outt = out + (size_t)t * (L * A);
    const int a0 = aq * 4;
    const int nj = (aq == 7) ? 2 : 4;
#pragma unroll
    for (int i = 0; i < 4; ++i) {
        if (lvalid[i]) {
            const int l = l0 + lg + 32 * i;
            float* o = outt + l * A + a0;
            for (int j = 0; j < nj; ++j) o[j] = acc[i][j];
        }
    }
}

extern "C" void kernel_launch(void* const* d_in, const int* in_sizes, int n_in,
                              void* d_out, int out_size, void* d_ws, size_t ws_size,
                              hipStream_t stream) {
    (void)in_sizes; (void)n_in; (void)out_size; (void)ws_size;
    const float* vp    = (const float*)d_in[0];
    const float* vs    = (const float*)d_in[1];
    const float* rho   = (const float*)d_in[2];
    const float* theta = (const float*)d_in[3];
    const float* wm    = (const float*)d_in[4];
    float* out   = (float*)d_out;
    float* ref_g = (float*)d_ws;                        // 19.66 MB
    float* wmT   = ref_g + (size_t)T * TRACE_STRIDE;    // + 256 KB

    transpose_wm<<<dim3(256), dim3(256), 0, stream>>>(wm, wmT);
    zoep_ref_kernel<<<dim3(T * 8), dim3(256), 0, stream>>>(vp, vs, rho, theta, ref_g);
    zoep_gemm_kernel<<<dim3(T * 2), dim3(256), 0, stream>>>(wmT, ref_g, out);
}

// Round 7
// 100.882 us; speedup vs baseline: 1.5329x; 1.5329x over previous
//
#include <hip/hip_runtime.h>

// Problem constants (from reference)
constexpr int L  = 250;   // layers
constexpr int T  = 600;   // traces
constexpr int A  = 30;    // angles

typedef _Float16 h8  __attribute__((ext_vector_type(8)));   // MFMA A/B frag (4 VGPR)
typedef float    f4  __attribute__((ext_vector_type(4)));   // MFMA C/D frag

// refT LDS row stride (halfs): 264 = 256+8 -> lane n hits bank 4n%32,
// only 2-way aliasing (free per m136); 16-B aligned (264*2=528=33*16).
constexpr int RT_LD = 264;

// ---------------- Kernel W: wm_h[m][k] = f16(wm[m][k]), padded 256x256 ----
__global__ __launch_bounds__(256)
void wm_to_h(const float* __restrict__ wm, _Float16* __restrict__ wmh)
{
    const int m = blockIdx.x;     // 0..255
    const int k = threadIdx.x;    // 0..255
    _Float16 v = (_Float16)0.0f;
    if (m < L && k < L) v = (_Float16)wm[m * L + k];
    wmh[m * 256 + k] = v;         // row-major, stride 256 halfs = 512 B
}

// ---------------- Fused kernel: one block per trace ----------------
// Phase 1: Zoeppritz Rpp (f32 Cramer + cofactor identity, fast rcp) ->
//          LDS refT[a][k] as f16 (a padded to 32, k to 256, zeros in pads).
// Phase 2: out[t] = wm @ ref via v_mfma_f32_16x16x32_f16.
//          Verified layouts: A[m=lane&15][k=quad*8+j], B[k=quad*8+j][n=lane&15],
//          C/D[row=quad*4+reg][col=lane&15].
__global__ __launch_bounds__(256)
void zoep_fused(const float* __restrict__ vp,
                const float* __restrict__ vs,
                const float* __restrict__ rho,
                const float* __restrict__ theta,
                const _Float16* __restrict__ wmh,
                float* __restrict__ out)
{
    __shared__ _Float16 refT[32 * RT_LD];   // 16.5 KB: refT[a][k]
    __shared__ float sth_s[32];
    __shared__ float cth_s[32];

    const int tid = threadIdx.x;
    const int t   = blockIdx.x;

    if (tid < 32) {
        const float th = (tid < A) ? theta[tid] : 0.0f;
        sth_s[tid] = sinf(th);
        cth_s[tid] = cosf(th);
    }
    __syncthreads();

    // ---- Phase 1: 8 k-groups x 4 angles per thread ----
    const int aq = tid & 7;
    const int a0 = aq << 2;          // angles a0..a0+3
    const int kb = tid >> 3;         // 0..31

    for (int g = 0; g < 8; ++g) {
        const int k = g * 32 + kb;   // covers 0..255 exactly
        float res[4] = {0.f, 0.f, 0.f, 0.f};

        if (k < L - 1) {
            const float a1 = vp[k * T + t];
            const float a2 = vp[(k + 1) * T + t];
            const float b1 = vs[k * T + t];
            const float b2 = vs[(k + 1) * T + t];
            const float r1 = rho[k * T + t];
            const float r2 = rho[(k + 1) * T + t];

            const float ra1  = __builtin_amdgcn_rcpf(a1);
            const float rb1  = r1 * b1, rb2 = r2 * b2;
            const float ra1r = r1 * a1, ra2r = r2 * a2;

#pragma unroll
            for (int j = 0; j < 4; ++j) {
                const float sth = sth_s[a0 + j];
                const float cth = cth_s[a0 + j];

                const float p   = sth * ra1;
                const float s2  = p * a2;               // |.| <= 0.84 < 1
                const float c2  = sqrtf(1.0f - s2 * s2);
                const float sp1 = p * b1;
                const float cp1 = sqrtf(1.0f - sp1 * sp1);
                const float sp2 = p * b2;
                const float cp2 = sqrtf(1.0f - sp2 * sp2);

                const float k1 = 1.0f - 2.0f * sp1 * sp1;
                const float k2 = 1.0f - 2.0f * sp2 * sp2;
                const float q1 = rb1 * k1;
                const float q2 = rb2 * k2;
                const float P1 = ra1r * k1;
                const float P2 = ra2r * k2;
                const float u1 = 2.0f * rb1 * sp1;
                const float u2 = 2.0f * rb2 * sp2;
                const float S1 = u1 * cp1;
                const float S2 = u2 * cp2;
                const float g1 = u1 * cth;
                const float g2 = u2 * c2;

                const float m00 = -sth, m01 = -cp1, m02 = s2,  m03 = cp2;
                const float m10 =  cth, m11 = -sp1, m12 = c2,  m13 = -sp2;
                const float m20 =  g1,  m21 =  q1,  m22 = g2,  m23 = q2;
                const float m30 = -P1,  m31 =  S1,  m32 = P2,  m33 = -S2;

                const float s3v = m01 * m12 - m11 * m02;
                const float s4v = m01 * m13 - m11 * m03;
                const float s5v = m02 * m13 - m12 * m03;
                const float c3v = m21 * m32 - m31 * m22;
                const float c4v = m21 * m33 - m31 * m23;
                const float c5v = m22 * m33 - m32 * m23;
                const float s0v = m00 * m11 - m10 * m01;
                const float s1v = m00 * m12 - m10 * m02;
                const float s2v = m00 * m13 - m10 * m03;
                const float c0v = m20 * m31 - m30 * m21;
                const float c1v = m20 * m32 - m30 * m22;
                const float c2v = m20 * m33 - m30 * m23;

                const float detM = s0v*c5v - s1v*c4v + s2v*c3v
                                 + s3v*c2v - s4v*c1v + s5v*c0v;
                const float A0 = m11*c5v - m12*c4v + m13*c3v;   // minor(0,0)
                const float A3 = m21*s5v - m22*s4v + m23*s3v;   // minor(3,0)

                const float num = m00 * A0 - m30 * A3;
                res[j] = 1.0f - 2.0f * num * __builtin_amdgcn_rcpf(detM);
            }
            if (aq == 7) { res[2] = 0.0f; res[3] = 0.0f; }   // a = 30,31 pad
        }
        // write transposed f16 (k>=249 and a-pads are zeros)
#pragma unroll
        for (int j = 0; j < 4; ++j)
            refT[(a0 + j) * RT_LD + k] = (_Float16)res[j];
    }
    __syncthreads();

    // ---- Phase 2: MFMA GEMM. wave w owns m-tiles w*4..w*4+3, both n-tiles.
    const int w    = tid >> 6;       // wave 0..3
    const int lane = tid & 63;
    const int quad = lane >> 4;      // 0..3
    const int n16  = lane & 15;

    f4 acc[4][2];
#pragma unroll
    for (int mi = 0; mi < 4; ++mi)
#pragma unroll
        for (int nt = 0; nt < 2; ++nt) acc[mi][nt] = (f4){0.f, 0.f, 0.f, 0.f};

#pragma unroll
    for (int ks = 0; ks < 8; ++ks) {                 // K = 8 x 32
        const int kofs = ks * 32 + quad * 8;
        const h8 b0 = *(const h8*)&refT[ n16       * RT_LD + kofs];
        const h8 b1 = *(const h8*)&refT[(16 + n16) * RT_LD + kofs];
#pragma unroll
        for (int mi = 0; mi < 4; ++mi) {
            const int m = (w * 4 + mi) * 16 + n16;   // wm row
            const h8 af = *(const h8*)&wmh[m * 256 + kofs];
            acc[mi][0] = __builtin_amdgcn_mfma_f32_16x16x32_f16(af, b0, acc[mi][0], 0, 0, 0);
            acc[mi][1] = __builtin_amdgcn_mfma_f32_16x16x32_f16(af, b1, acc[mi][1], 0, 0, 0);
        }
    }

    // ---- Epilogue: D[row=quad*4+r][col=n16] -> out[t][l][a] ----
    float* outt = out + (size_t)t * (L * A);
#pragma unroll
    for (int mi = 0; mi < 4; ++mi) {
        const int mbase = (w * 4 + mi) * 16 + quad * 4;
#pragma unroll
        for (int nt = 0; nt < 2; ++nt) {
            const int a = nt * 16 + n16;
            if (a < A) {
#pragma unroll
                for (int r = 0; r < 4; ++r) {
                    const int l = mbase + r;
                    if (l < L) outt[l * A + a] = acc[mi][nt][r];
                }
            }
        }
    }
}

extern "C" void kernel_launch(void* const* d_in, const int* in_sizes, int n_in,
                              void* d_out, int out_size, void* d_ws, size_t ws_size,
                              hipStream_t stream) {
    (void)in_sizes; (void)n_in; (void)out_size; (void)ws_size;
    const float* vp    = (const float*)d_in[0];
    const float* vs    = (const float*)d_in[1];
    const float* rho   = (const float*)d_in[2];
    const float* theta = (const float*)d_in[3];
    const float* wm    = (const float*)d_in[4];
    float* out = (float*)d_out;
    _Float16* wmh = (_Float16*)d_ws;   // 256*256*2 = 128 KB

    wm_to_h<<<dim3(256), dim3(256), 0, stream>>>(wm, wmh);
    zoep_fused<<<dim3(T), dim3(256), 0, stream>>>(vp, vs, rho, theta, wmh, out);
}

// Round 12
// 99.913 us; speedup vs baseline: 1.5477x; 1.0097x over previous
//
#include <hip/hip_runtime.h>

// Problem constants (from reference)
constexpr int L  = 250;   // layers
constexpr int T  = 600;   // traces
constexpr int A  = 30;    // angles

typedef _Float16 h8  __attribute__((ext_vector_type(8)));   // MFMA A/B frag (4 VGPR)
typedef float    f4  __attribute__((ext_vector_type(4)));   // MFMA C/D frag

// refT LDS row stride (halfs): 264 = 256+8 -> 16-B aligned rows, 2-way-free banks
constexpr int RT_LD = 264;

// ---------------- Single fused kernel: one block per trace ----------------
// NO workspace, NO producer kernel: R8-R11's non-deterministic failures
// (identical binaries, varying absmax incl. f16-poison-magnitude values)
// implicate the wm_to_h -> zoep_fused handoff of f16 wm through d_ws.
// Phase 2 instead converts the pristine f32 `wm` INPUT to f16 in-register
// (same rounding as the old wm_to_h => identical numerics to R7's pass).
//
// Phase 1 (one k per thread): 6 input loads once into registers — one load
//   instr per array per wave puts 64 distinct lines in flight. Uniform
//   control flow: clamped load index, validity masked at the refT write.
// Phase 2: out[t] = wm @ ref via v_mfma_f32_16x16x32_f16.
//   Verified layouts: A[m=lane&15][k=quad*8+j], B[k=quad*8+j][n=lane&15],
//   C/D[row=quad*4+reg][col=lane&15].
__global__ __launch_bounds__(256)
void zoep_fused(const float* __restrict__ vp,
                const float* __restrict__ vs,
                const float* __restrict__ rho,
                const float* __restrict__ theta,
                const float* __restrict__ wm,
                float* __restrict__ out)
{
    __shared__ _Float16 refT[32 * RT_LD];   // 16.5 KB: refT[a][k]
    __shared__ float sth_s[32];
    __shared__ float cth_s[32];

    const int tid = threadIdx.x;
    const int t   = blockIdx.x;

    if (tid < 32) {
        const float th = (tid < A) ? theta[tid] : 0.0f;
        sth_s[tid] = sinf(th);
        cth_s[tid] = cosf(th);
    }
    __syncthreads();

    // ---- Phase 1: thread owns interface k = tid (0..255) ----
    const int  k     = tid;
    const bool valid = (k < L - 1);
    const int  kc    = valid ? k : (L - 2);   // clamped: loads always in-bounds

    const float a1 = vp[kc * T + t];          // lane-distinct lines, 1 instr/array
    const float a2 = vp[(kc + 1) * T + t];
    const float b1 = vs[kc * T + t];
    const float b2 = vs[(kc + 1) * T + t];
    const float r1 = rho[kc * T + t];
    const float r2 = rho[(kc + 1) * T + t];

    const float ra1  = __builtin_amdgcn_rcpf(a1);
    const float rb1  = r1 * b1, rb2 = r2 * b2;
    const float ra1r = r1 * a1, ra2r = r2 * a2;

#pragma unroll 2
    for (int a = 0; a < A; ++a) {
        const float sth = sth_s[a];           // LDS broadcast (uniform a)
        const float cth = cth_s[a];

        const float p   = sth * ra1;
        const float s2  = p * a2;             // |.| <= 0.84 < 1 (input ranges)
        const float c2  = sqrtf(1.0f - s2 * s2);
        const float sp1 = p * b1;
        const float cp1 = sqrtf(1.0f - sp1 * sp1);
        const float sp2 = p * b2;
        const float cp2 = sqrtf(1.0f - sp2 * sp2);

        const float k1 = 1.0f - 2.0f * sp1 * sp1;
        const float k2 = 1.0f - 2.0f * sp2 * sp2;
        const float q1 = rb1 * k1;
        const float q2 = rb2 * k2;
        const float P1 = ra1r * k1;
        const float P2 = ra2r * k2;
        const float u1 = 2.0f * rb1 * sp1;
        const float u2 = 2.0f * rb2 * sp2;
        const float S1 = u1 * cp1;
        const float S2 = u2 * cp2;
        const float g1 = u1 * cth;
        const float g2 = u2 * c2;

        // M (row-major)
        const float m00 = -sth, m01 = -cp1, m02 = s2,  m03 = cp2;
        const float m10 =  cth, m11 = -sp1, m12 = c2,  m13 = -sp2;
        const float m20 =  g1,  m21 =  q1,  m22 = g2,  m23 = q2;
        const float m30 = -P1,  m31 =  S1,  m32 = P2,  m33 = -S2;

        // 2x2 minors: s* rows{0,1}, c* rows{2,3}
        const float s3v = m01 * m12 - m11 * m02;
        const float s4v = m01 * m13 - m11 * m03;
        const float s5v = m02 * m13 - m12 * m03;
        const float c3v = m21 * m32 - m31 * m22;
        const float c4v = m21 * m33 - m31 * m23;
        const float c5v = m22 * m33 - m32 * m23;
        const float s0v = m00 * m11 - m10 * m01;
        const float s1v = m00 * m12 - m10 * m02;
        const float s2v = m00 * m13 - m10 * m03;
        const float c0v = m20 * m31 - m30 * m21;
        const float c1v = m20 * m32 - m30 * m22;
        const float c2v = m20 * m33 - m30 * m23;

        const float detM = s0v*c5v - s1v*c4v + s2v*c3v
                         + s3v*c2v - s4v*c1v + s5v*c0v;
        const float A0 = m11*c5v - m12*c4v + m13*c3v;   // minor(0,0)
        const float A3 = m21*s5v - m22*s4v + m23*s3v;   // minor(3,0)

        const float num = m00 * A0 - m30 * A3;
        const float res = 1.0f - 2.0f * num * __builtin_amdgcn_rcpf(detM);

        refT[a * RT_LD + k] = (_Float16)(valid ? res : 0.0f);
    }
    // zero pad rows a = 30, 31 (column k)
    refT[30 * RT_LD + k] = (_Float16)0.0f;
    refT[31 * RT_LD + k] = (_Float16)0.0f;
    __syncthreads();

    // ---- Phase 2: MFMA GEMM. wave w owns m-tiles w*4..w*4+3, both n-tiles.
    const int w    = tid >> 6;       // wave 0..3
    const int lane = tid & 63;
    const int quad = lane >> 4;      // 0..3
    const int n16  = lane & 15;

    f4 acc[4][2];
#pragma unroll
    for (int mi = 0; mi < 4; ++mi)
#pragma unroll
        for (int nt = 0; nt < 2; ++nt) acc[mi][nt] = (f4){0.f, 0.f, 0.f, 0.f};

#pragma unroll
    for (int ks = 0; ks < 8; ++ks) {                 // K = 8 x 32
        const int kofs = ks * 32 + quad * 8;
        const h8 b0 = *(const h8*)&refT[ n16       * RT_LD + kofs];
        const h8 b1 = *(const h8*)&refT[(16 + n16) * RT_LD + kofs];
#pragma unroll
        for (int mi = 0; mi < 4; ++mi) {
            const int m    = (w * 4 + mi) * 16 + n16;    // logical wm row 0..255
            const int rowc = (m < L) ? m : (L - 1);      // clamped (store-masked)
            const float* wrow = wm + rowc * L;

            // A-fragment: 8 f32 -> f16, in-bounds via pair clamp + zero-select.
            // Cols >= 250 multiply zero refT columns; zero-select keeps them
            // finite AND all loads inside wm[0..62499].
            h8 af;
#pragma unroll
            for (int c = 0; c < 4; ++c) {
                const int col  = kofs + 2 * c;                    // even
                const int colc = (col <= L - 2) ? col : (L - 2);  // pair start <= 248
                const float2 f = *(const float2*)(wrow + colc);   // 8B-aligned
                af[2 * c]     = (_Float16)((col     < L) ? f.x : 0.0f);
                af[2 * c + 1] = (_Float16)((col + 1 < L) ? f.y : 0.0f);
            }

            acc[mi][0] = __builtin_amdgcn_mfma_f32_16x16x32_f16(af, b0, acc[mi][0], 0, 0, 0);
            acc[mi][1] = __builtin_amdgcn_mfma_f32_16x16x32_f16(af, b1, acc[mi][1], 0, 0, 0);
        }
    }

    // ---- Epilogue: D[row=quad*4+r][col=n16] -> out[t][l][a] ----
    float* outt = out + (size_t)t * (L * A);
#pragma unroll
    for (int mi = 0; mi < 4; ++mi) {
        const int mbase = (w * 4 + mi) * 16 + quad * 4;
#pragma unroll
        for (int nt = 0; nt < 2; ++nt) {
            const int a = nt * 16 + n16;
            if (a < A) {
#pragma unroll
                for (int r = 0; r < 4; ++r) {
                    const int l = mbase + r;
                    if (l < L) outt[l * A + a] = acc[mi][nt][r];
                }
            }
        }
    }
}

extern "C" void kernel_launch(void* const* d_in, const int* in_sizes, int n_in,
                              void* d_out, int out_size, void* d_ws, size_t ws_size,
                              hipStream_t stream) {
    (void)in_sizes; (void)n_in; (void)out_size; (void)d_ws; (void)ws_size;
    const float* vp    = (const float*)d_in[0];
    const float* vs    = (const float*)d_in[1];
    const float* rho   = (const float*)d_in[2];
    const float* theta = (const float*)d_in[3];
    const float* wm    = (const float*)d_in[4];
    float* out = (float*)d_out;

    zoep_fused<<<dim3(T), dim3(256), 0, stream>>>(vp, vs, rho, theta, wm, out);
}